// Round 16
// baseline (1478.648 us; speedup 1.0000x reference)
//
#include <hip/hip_runtime.h>
#include <hip/hip_bf16.h>
#include <stdint.h>

#define NBLK   4
#define HDIM   256
#define NHEADS 8
#define RDIM   20
#define CDIM   128
#define PDIM   190
#define BDIM   2
#define FDIM   1024
#define NROWS  (BDIM*PDIM*CDIM)             // 48640
#define NF     ((size_t)NROWS*(size_t)HDIM) // 12,451,840
#define HROWS  (NROWS/2)                    // 24320

typedef __attribute__((ext_vector_type(8))) short bf16x8;
typedef __attribute__((ext_vector_type(4))) float f32x4;

__device__ __forceinline__ short f2b(float f){
    uint32_t u = __float_as_uint(f);
    u += 0x7fff + ((u >> 16) & 1);          // RNE
    return (short)(u >> 16);
}
__device__ __forceinline__ float b2f(short s){
    return __uint_as_float(((uint32_t)(uint16_t)s) << 16);
}
__device__ __forceinline__ int cvtpk(float a, float b){
    int r;
    asm("v_cvt_pk_bf16_f32 %0, %1, %2" : "=v"(r) : "v"(a), "v"(b));
    return r;
}
// gelu(tanh approx) == x * sigmoid(2*k0*(x + k1*x^3))
__device__ __forceinline__ float gelu_fast(float x){
    const float tk0 = 1.5957691216057308f;   // 2*sqrt(2/pi)
    const float k1  = 0.044715f;
    float u = tk0*(x + k1*x*x*x);
    return x / (1.0f + __expf(-u));
}
__device__ __forceinline__ void async16(const void* g, void* l){
    __builtin_amdgcn_global_load_lds(
        (const __attribute__((address_space(1))) void*)g,
        (__attribute__((address_space(3))) void*)l, 16, 0, 0);
}
// bijective XCD-chunking swizzle (m204)
__device__ __forceinline__ int xcd_swz(int nwg){
    int orig = blockIdx.x;
    int q = nwg >> 3, r = nwg & 7;
    int xcd = orig & 7, idx = orig >> 3;
    return ((xcd < r) ? xcd*(q+1) : r*(q+1) + (xcd - r)*q) + idx;
}

// ---------------------------------------------------------------------------
// Embedding + pairwise row-sum + fused LN1(block0). One wave per row.
// ---------------------------------------------------------------------------
__global__ __launch_bounds__(256) void embed_ln_kernel(
    const int* __restrict__ tokens, const float* __restrict__ emb,
    const float* __restrict__ g, const float* __restrict__ bta,
    float* __restrict__ x, short* __restrict__ hb)
{
    int n    = blockIdx.x*4 + (threadIdx.x >> 6);
    int lane = threadIdx.x & 63;
    int c  = n % CDIM;
    int bp = n / CDIM;
    int p  = bp % PDIM;
    int b  = bp / PDIM;
    int i = 0, rem = p;
    while (rem >= (RDIM - 1 - i)) { rem -= (RDIM - 1 - i); ++i; }
    int j = i + 1 + rem;
    int t1 = tokens[(b*RDIM + i)*CDIM + c];
    int t2 = tokens[(b*RDIM + j)*CDIM + c];
    float4 e1 = *(const float4*)(emb + (size_t)t1*HDIM + lane*4);
    float4 e2 = *(const float4*)(emb + (size_t)t2*HDIM + lane*4);
    float4 v; v.x = e1.x+e2.x; v.y = e1.y+e2.y; v.z = e1.z+e2.z; v.w = e1.w+e2.w;
    *(float4*)(x + (size_t)n*HDIM + lane*4) = v;

    float s1 = v.x + v.y + v.z + v.w;
    float s2 = v.x*v.x + v.y*v.y + v.z*v.z + v.w*v.w;
    #pragma unroll
    for (int off = 1; off < 64; off <<= 1) {
        s1 += __shfl_xor(s1, off);
        s2 += __shfl_xor(s2, off);
    }
    float mu  = s1 * (1.0f/HDIM);
    float var = s2 * (1.0f/HDIM) - mu*mu;
    float inv = rsqrtf(var + 1e-5f);
    float4 gg = *(const float4*)(g   + lane*4);
    float4 bb = *(const float4*)(bta + lane*4);
    short4 o;
    o.x = f2b((v.x - mu)*inv*gg.x + bb.x);
    o.y = f2b((v.y - mu)*inv*gg.y + bb.y);
    o.z = f2b((v.z - mu)*inv*gg.z + bb.z);
    o.w = f2b((v.w - mu)*inv*gg.w + bb.w);
    *(short4*)(hb + (size_t)n*HDIM + lane*4) = o;
}

// ---------------------------------------------------------------------------
// LayerNorm fp32 -> bf16. One wave per row, float4 per lane.
// ---------------------------------------------------------------------------
__global__ __launch_bounds__(256) void ln_kernel(
    const float* __restrict__ X, const float* __restrict__ g,
    const float* __restrict__ bta, short* __restrict__ Out)
{
    int row  = blockIdx.x*4 + (threadIdx.x >> 6);
    int lane = threadIdx.x & 63;
    float4 v = *(const float4*)(X + (size_t)row*HDIM + lane*4);
    float s1 = v.x + v.y + v.z + v.w;
    float s2 = v.x*v.x + v.y*v.y + v.z*v.z + v.w*v.w;
    #pragma unroll
    for (int off = 1; off < 64; off <<= 1) {
        s1 += __shfl_xor(s1, off);
        s2 += __shfl_xor(s2, off);
    }
    float mu  = s1 * (1.0f/HDIM);
    float var = s2 * (1.0f/HDIM) - mu*mu;
    float inv = rsqrtf(var + 1e-5f);
    float4 gg = *(const float4*)(g   + lane*4);
    float4 bb = *(const float4*)(bta + lane*4);
    short4 o;
    o.x = f2b((v.x - mu)*inv*gg.x + bb.x);
    o.y = f2b((v.y - mu)*inv*gg.y + bb.y);
    o.z = f2b((v.z - mu)*inv*gg.z + bb.z);
    o.w = f2b((v.w - mu)*inv*gg.w + bb.w);
    *(short4*)(Out + (size_t)row*HDIM + lane*4) = o;
}

// ---------------------------------------------------------------------------
// Weight transpose+convert: in f32 [K][M] -> out bf16 [M][K]
// ---------------------------------------------------------------------------
__global__ __launch_bounds__(256) void tconv_kernel(
    const float* __restrict__ in, short* __restrict__ out,
    int K, int M, size_t inz, size_t outz)
{
    __shared__ float t[32][33];
    in  += (size_t)blockIdx.z * inz;
    out += (size_t)blockIdx.z * outz;
    int m0 = blockIdx.x*32, k0 = blockIdx.y*32;
    int r = threadIdx.x >> 5, c = threadIdx.x & 31;
    #pragma unroll
    for (int i = 0; i < 4; ++i)
        t[r + i*8][c] = in[(size_t)(k0 + r + i*8)*M + m0 + c];
    __syncthreads();
    #pragma unroll
    for (int i = 0; i < 4; ++i) {
        int rr = r + i*8;
        out[(size_t)(m0 + rr)*K + k0 + c] = f2b(t[c][rr]);
    }
}

// ---------------------------------------------------------------------------
// bf16 MFMA GEMM, 2-buffer prefetch + LDS-staged coalesced bf16 C-stores.
// EPI 0: QKV split store bf16 (Q pre-scaled by log2(e)/sqrt(d) for exp2 attn)
// EPI 1: OutF += acc
// EPI 2: bf16(gelu(acc+bias))
// EPI 3: OutF += acc + bias
// EPI 4: OutF += acc + bias; OB0 = bf16(result)
// ---------------------------------------------------------------------------
template<int EPI>
__global__ __launch_bounds__(256) void mgemm_kernel(
    const short* __restrict__ A, const short* __restrict__ Wt,
    const float* __restrict__ bias,
    float* __restrict__ OutF,
    short* __restrict__ OB0, short* __restrict__ OB1, short* __restrict__ OB2,
    int K, int M, int ncol)
{
    __shared__ __align__(16) short smem[16384];   // As[2]+Bs[2]; reused as C[128][128]
    short* As0 = smem;
    short* Bs0 = smem + 8192;
    const int tid  = threadIdx.x;
    const int lane = tid & 63, wid = tid >> 6;
    const int lq = lane & 15, lk = lane >> 4;
    const int wr = wid >> 1, wc = wid & 1;
    const int bid  = xcd_swz(gridDim.x);
    const int row0 = (bid / ncol) * 128, col0 = (bid % ncol) * 128;

    f32x4 acc[4][4] = {};

    auto stage = [&](int buf, int k0) {
        #pragma unroll
        for (int u = 0; u < 2; ++u) {
            int b   = wid*1024 + lane*16 + u*4096;
            int r   = b >> 6;
            int c16 = (b >> 4) & 3;
            int cs  = (c16 ^ ((r >> 1) & 3)) * 8;
            async16(A  + (size_t)(row0 + r)*K + k0 + cs, (char*)(As0 + buf*4096) + b);
            async16(Wt + (size_t)(col0 + r)*K + k0 + cs, (char*)(Bs0 + buf*4096) + b);
        }
    };

    stage(0, 0);
    const int NTK = K >> 5;
    for (int t = 0; t < NTK; ++t) {
        const int cur = t & 1;
        asm volatile("s_waitcnt vmcnt(0)" ::: "memory");
        __builtin_amdgcn_s_barrier();
        __builtin_amdgcn_sched_barrier(0);
        if (t + 1 < NTK) stage(cur ^ 1, (t + 1)*32);

        bf16x8 af[4], bfr[4];
        #pragma unroll
        for (int m = 0; m < 4; ++m) {
            int row = wr*64 + m*16 + lq;
            af[m] = *(const bf16x8*)((const char*)(As0 + cur*4096) + row*64 + ((lk ^ ((lq >> 1) & 3)) << 4));
        }
        #pragma unroll
        for (int n = 0; n < 4; ++n) {
            int row = wc*64 + n*16 + lq;
            bfr[n] = *(const bf16x8*)((const char*)(Bs0 + cur*4096) + row*64 + ((lk ^ ((lq >> 1) & 3)) << 4));
        }
        #pragma unroll
        for (int m = 0; m < 4; ++m)
            #pragma unroll
            for (int n = 0; n < 4; ++n)
                acc[m][n] = __builtin_amdgcn_mfma_f32_16x16x32_bf16(af[m], bfr[n], acc[m][n], 0, 0, 0);
    }

    // D layout: row = (lane>>4)*4 + reg, col = lane&15
    if (EPI == 1 || EPI == 3) {
        const int rb  = row0 + wr*64 + (lk << 2);
        const int cb0 = col0 + wc*64 + lq;
        #pragma unroll
        for (int m = 0; m < 4; ++m)
            #pragma unroll
            for (int n = 0; n < 4; ++n) {
                int col = cb0 + n*16;
                #pragma unroll
                for (int r = 0; r < 4; ++r) {
                    int row = rb + m*16 + r;
                    float vv = acc[m][n][r];
                    if (EPI == 3) vv += bias[col];
                    OutF[(size_t)row*HDIM + col] += vv;
                }
            }
        return;
    }

    // ---- bf16 epilogues: transform -> LDS C-stage -> coalesced 16B stores
    float bias8[4];
    if (EPI == 2 || EPI == 4) {
        #pragma unroll
        for (int n = 0; n < 4; ++n) bias8[n] = bias[col0 + wc*64 + n*16 + lq];
    }
    const int sec = col0 >> 8;                     // EPI0: uniform per block
    // Q pre-scale: log2(e)/sqrt(32) so attn uses native v_exp_f32 (2^x)
    const float qsc = (EPI == 0 && sec == 0) ? 0.2550540018992861f : 1.0f;

    __syncthreads();   // all waves done reading staging LDS
    #pragma unroll
    for (int m = 0; m < 4; ++m) {
        #pragma unroll
        for (int n = 0; n < 4; ++n) {
            #pragma unroll
            for (int r = 0; r < 4; ++r) {
                int lrow = wr*64 + m*16 + lk*4 + r;
                int lcol = wc*64 + n*16 + lq;
                float vv = acc[m][n][r];
                if (EPI == 0) vv *= qsc;
                else if (EPI == 2) vv = gelu_fast(vv + bias8[n]);
                else { // EPI 4
                    int row = row0 + lrow, col = col0 + lcol;
                    float xo = OutF[(size_t)row*HDIM + col] + vv + bias8[n];
                    OutF[(size_t)row*HDIM + col] = xo;
                    vv = xo;
                }
                int byte = (lrow*256 + lcol*2) ^ ((lrow & 7) << 4);
                *(short*)((char*)smem + byte) = (short)cvtpk(vv, vv);
            }
        }
    }
    __syncthreads();

    short* obase;
    int ostride, ocol;
    if (EPI == 0) {
        obase = (sec == 0) ? OB0 : ((sec == 1) ? OB1 : OB2);
        ostride = HDIM; ocol = col0 & 255;
    } else if (EPI == 2) {
        obase = OB0; ostride = M; ocol = col0;
    } else {
        obase = OB0; ostride = HDIM; ocol = col0;
    }
    #pragma unroll
    for (int it = 0; it < 8; ++it) {
        int u    = it*256 + tid;
        int lrow = u >> 4;
        int uc   = u & 15;
        int su   = uc ^ (lrow & 7);
        int4 w = *(const int4*)((const char*)smem + lrow*256 + su*16);
        *(int4*)(obase + (size_t)(row0 + lrow)*ostride + ocol + uc*8) = w;
    }
}

// ---------------------------------------------------------------------------
// MFMA attention, 8 waves (512 thr). One block per (b,other,head); grid
// XCD-swizzled. Q pre-scaled by log2(e)/sqrt(d) -> exp2-domain softmax,
// no max-sub (clamp 126), denominator via ones-B MFMA.
// K staged [LP][32] source-swizzled; V transposed Vt[32][LP] row-XOR;
// per-wave P [16][LP] row-XOR. 8 waves halve per-wave chunk serialization
// (row: 12 tiles -> <=2/wave; col: 8 -> 1/wave) and raise waves/CU.
// ---------------------------------------------------------------------------
template<int LP>
__global__ __launch_bounds__(512) void attn_mfma(
    const short* __restrict__ Q, const short* __restrict__ K,
    const short* __restrict__ V, short* __restrict__ O,
    int Lreal, int isRow)
{
    constexpr int NT  = LP/16;     // key tiles (= q-row tiles)
    constexpr int NKT = LP/32;     // PV K-steps
    constexpr int LPB = LP*2;      // P row bytes

    __shared__ short Ks[LP*32];
    __shared__ short Vt[32*LP];
    __shared__ short Ps[8*16*LP];

    const int bid  = xcd_swz(gridDim.x);
    const int head = bid & 7;
    size_t base; int S;
    if (isRow) {
        int c = (bid >> 3) & (CDIM-1);
        int b = bid >> 10;
        base = ((size_t)b*PDIM*CDIM + c)*HDIM + head*32;
        S = CDIM*HDIM;
    } else {
        int p = (bid >> 3) % PDIM;
        int b = bid / (8*PDIM);
        base = ((size_t)(b*PDIM + p)*CDIM)*HDIM + head*32;
        S = HDIM;
    }

    const int tid  = threadIdx.x;
    const int lane = tid & 63, wid = tid >> 6;
    const int lq = lane & 15, lk = lane >> 4;

    // ---- stage K [LP][32]: linear LDS dest, source-swizzled 16B units
    for (int t16 = tid; t16 < LP*4; t16 += 512) {
        int row = t16 >> 2;
        int rc  = row < Lreal ? row : Lreal-1;
        int cs  = ((t16 & 3) ^ ((row >> 1) & 3)) * 8;
        async16(K + base + (size_t)rc*S + cs, (char*)Ks + (size_t)t16*16);
    }
    // ---- stage V transposed with XOR swizzle: Vt[d][key], byte ^= (d&7)<<4
    for (int e = tid; e < LP*8; e += 512) {
        int row = e >> 3;
        int d4  = (e & 7)*4;
        int rc  = row < Lreal ? row : Lreal-1;
        short4 v4 = *(const short4*)(V + base + (size_t)rc*S + d4);
        #pragma unroll
        for (int j = 0; j < 4; ++j) {
            int d = d4 + j;
            int off = ((d*LP + row)*2) ^ ((d & 7) << 4);
            *(short*)((char*)Vt + off) = ((const short*)&v4)[j];
        }
    }
    __syncthreads();

    char* pbase = (char*)Ps + wid*(16*LPB);
    const f32x4 zero = {0.f, 0.f, 0.f, 0.f};
    const bf16x8 ones = {(short)0x3F80,(short)0x3F80,(short)0x3F80,(short)0x3F80,
                         (short)0x3F80,(short)0x3F80,(short)0x3F80,(short)0x3F80};

    #pragma unroll 1
    for (int cc = 0; cc < (NT + 7)/8; ++cc) {
        const int chunk = wid + cc*8;
        if (chunk >= NT) break;                 // wave-uniform
        const int qrow0 = chunk*16;

        int qr = qrow0 + lq; if (qr >= Lreal) qr = Lreal-1;
        bf16x8 qa = *(const bf16x8*)(Q + base + (size_t)qr*S + lk*8);

        f32x4 s[NT];
        #pragma unroll
        for (int t = 0; t < NT; ++t) {
            bf16x8 kb = *(const bf16x8*)((const char*)Ks + (t*16 + lq)*64 + ((lk ^ ((lq >> 1) & 3)) << 4));
            s[t] = __builtin_amdgcn_mfma_f32_16x16x32_bf16(qa, kb, zero, 0, 0, 0);
        }
        if ((NT-1)*16 + lq >= Lreal) {
            #pragma unroll
            for (int r = 0; r < 4; ++r) s[NT-1][r] = -1e30f;
        }

        // P = exp2(s) -> bf16 LDS (s already in log2 domain; dead keys -> 0)
        #pragma unroll
        for (int t = 0; t < NT; ++t)
            #pragma unroll
            for (int r = 0; r < 4; ++r) {
                float p = exp2f(fminf(s[t][r], 126.f));
                int row = lk*4 + r, col = t*16 + lq;
                int off = (row*LPB + col*2) ^ ((row & 7) << 4);
                *(short*)(pbase + off) = (short)cvtpk(p, p);
            }
        asm volatile("s_waitcnt lgkmcnt(0)" ::: "memory");
        __builtin_amdgcn_sched_barrier(0);

        // PV + ones-denominator
        f32x4 acc0 = zero, acc1 = zero, accs = zero;
        #pragma unroll
        for (int kt = 0; kt < NKT; ++kt) {
            bf16x8 pa = *(const bf16x8*)(pbase + ((lq*LPB + kt*64 + lk*16) ^ ((lq & 7) << 4)));
            bf16x8 v0 = *(const bf16x8*)((char*)Vt + ((lq*LPB      + kt*64 + lk*16) ^ ((lq & 7) << 4)));
            bf16x8 v1 = *(const bf16x8*)((char*)Vt + (((16+lq)*LPB + kt*64 + lk*16) ^ ((lq & 7) << 4)));
            acc0 = __builtin_amdgcn_mfma_f32_16x16x32_bf16(pa, v0, acc0, 0, 0, 0);
            acc1 = __builtin_amdgcn_mfma_f32_16x16x32_bf16(pa, v1, acc1, 0, 0, 0);
            accs = __builtin_amdgcn_mfma_f32_16x16x32_bf16(pa, ones, accs, 0, 0, 0);
        }
        asm volatile("s_waitcnt lgkmcnt(0)" ::: "memory");
        __builtin_amdgcn_sched_barrier(0);

        // ---- coalesced O-store: stage 16x32 bf16 tile in pbase (lk-XOR units)
        #pragma unroll
        for (int r = 0; r < 4; ++r) {
            float inv = 1.0f / accs[r];
            int row = lk*4 + r;
            int b0 = row*64 + ((lq*2)        ^ (lk << 4));
            int b1 = row*64 + ((32 + lq*2)   ^ (lk << 4));
            *(short*)(pbase + b0) = (short)cvtpk(acc0[r]*inv, acc0[r]*inv);
            *(short*)(pbase + b1) = (short)cvtpk(acc1[r]*inv, acc1[r]*inv);
        }
        asm volatile("s_waitcnt lgkmcnt(0)" ::: "memory");
        __builtin_amdgcn_sched_barrier(0);
        {
            int rr  = lane >> 2, uc = lane & 3;
            int row = qrow0 + rr;
            if (row < Lreal) {
                int lkw = rr >> 2;                      // writer's lk for this row
                int4 w = *(const int4*)(pbase + rr*64 + uc*16);
                *(int4*)(O + base + (size_t)row*S + (uc ^ lkw)*8) = w;
            }
        }
        __builtin_amdgcn_sched_barrier(0);   // keep next chunk's P writes behind these reads
    }
}

// ---------------------------------------------------------------------------
__global__ __launch_bounds__(256) void gemv_head(
    const short* __restrict__ T, const float* __restrict__ w,
    const float* __restrict__ bias, float* __restrict__ y)
{
    int row  = blockIdx.x*4 + (threadIdx.x >> 6);
    int lane = threadIdx.x & 63;
    const short* t = T + (size_t)row*FDIM;
    float acc = 0.f;
    #pragma unroll
    for (int it = 0; it < 4; ++it) {
        int ci = it*64 + lane;
        short4 tv = *(const short4*)(t + ci*4);
        float4 wv = *(const float4*)(w + ci*4);
        acc += b2f(tv.x)*wv.x + b2f(tv.y)*wv.y + b2f(tv.z)*wv.z + b2f(tv.w)*wv.w;
    }
    #pragma unroll
    for (int off = 1; off < 64; off <<= 1) acc += __shfl_xor(acc, off);
    if (lane == 0) y[row] = acc + bias[0];
}

__global__ __launch_bounds__(128) void final_kernel(
    const float* __restrict__ y, const float* __restrict__ uW,
    const float* __restrict__ ub, float* __restrict__ out)
{
    int bp = blockIdx.x;
    int c  = threadIdx.x;
    float v = y[(size_t)bp*CDIM + c]*uW[c];
    #pragma unroll
    for (int off = 1; off < 64; off <<= 1) v += __shfl_xor(v, off);
    __shared__ float r[2];
    if ((c & 63) == 0) r[c >> 6] = v;
    __syncthreads();
    if (c == 0) out[bp] = r[0] + r[1] + ub[0];
}

// ---------------------------------------------------------------------------
extern "C" void kernel_launch(void* const* d_in, const int* in_sizes, int n_in,
                              void* d_out, int out_size, void* d_ws, size_t ws_size,
                              hipStream_t stream)
{
    const int*   tokens = (const int*)  d_in[0];
    const float* emb    = (const float*)d_in[1];
    const float* ln1_g  = (const float*)d_in[2];
    const float* ln1_b  = (const float*)d_in[3];
    const float* rWq    = (const float*)d_in[4];
    const float* rWk    = (const float*)d_in[5];
    const float* rWv    = (const float*)d_in[6];
    const float* rWo    = (const float*)d_in[7];
    const float* ln2_g  = (const float*)d_in[8];
    const float* ln2_b  = (const float*)d_in[9];
    const float* cWq    = (const float*)d_in[10];
    const float* cWk    = (const float*)d_in[11];
    const float* cWv    = (const float*)d_in[12];
    const float* cWo    = (const float*)d_in[13];
    const float* ln3_g  = (const float*)d_in[14];
    const float* ln3_b  = (const float*)d_in[15];
    const float* fW1    = (const float*)d_in[16];
    const float* fb1    = (const float*)d_in[17];
    const float* fW2    = (const float*)d_in[18];
    const float* fb2    = (const float*)d_in[19];
    const float* pW1    = (const float*)d_in[20];
    const float* pb1    = (const float*)d_in[21];
    const float* pW2    = (const float*)d_in[22];
    const float* pb2    = (const float*)d_in[23];
    const float* uW     = (const float*)d_in[24];
    const float* ub     = (const float*)d_in[25];

    float* x  = (float*)d_ws;
    short* q  = (short*)(x + NF);
    short* k  = q + NF;
    short* v  = k + NF;
    short* hb = v + NF;
    float* y  = (float*)(hb + NF);
    short* wts = (short*)(y + NROWS);
    short* w_rqkv = wts;
    short* w_cqkv = w_rqkv + 4*768*256;
    short* w_ro   = w_cqkv + 4*768*256;
    short* w_co   = w_ro   + 4*256*256;
    short* w_f1   = w_co   + 4*256*256;
    short* w_f2   = w_f1   + (size_t)4*1024*256;
    short* w_p1   = w_f2   + (size_t)4*1024*256;
    short* tb = q;

    const size_t HH = 65536, HF = 262144, QZ = 768*256;

    tconv_kernel<<<dim3(8,8,NBLK),   256, 0, stream>>>(rWq, w_rqkv,          256, 256,  HH, QZ);
    tconv_kernel<<<dim3(8,8,NBLK),   256, 0, stream>>>(rWk, w_rqkv + 65536,  256, 256,  HH, QZ);
    tconv_kernel<<<dim3(8,8,NBLK),   256, 0, stream>>>(rWv, w_rqkv + 131072, 256, 256,  HH, QZ);
    tconv_kernel<<<dim3(8,8,NBLK),   256, 0, stream>>>(rWo, w_ro,            256, 256,  HH, HH);
    tconv_kernel<<<dim3(8,8,NBLK),   256, 0, stream>>>(cWq, w_cqkv,          256, 256,  HH, QZ);
    tconv_kernel<<<dim3(8,8,NBLK),   256, 0, stream>>>(cWk, w_cqkv + 65536,  256, 256,  HH, QZ);
    tconv_kernel<<<dim3(8,8,NBLK),   256, 0, stream>>>(cWv, w_cqkv + 131072, 256, 256,  HH, QZ);
    tconv_kernel<<<dim3(8,8,NBLK),   256, 0, stream>>>(cWo, w_co,            256, 256,  HH, HH);
    tconv_kernel<<<dim3(32,8,NBLK),  256, 0, stream>>>(fW1, w_f1,            256, 1024, HF, HF);
    tconv_kernel<<<dim3(8,32,NBLK),  256, 0, stream>>>(fW2, w_f2,            1024, 256, HF, HF);
    tconv_kernel<<<dim3(32,8,1),     256, 0, stream>>>(pW1, w_p1,            256, 1024, HF, HF);

    embed_ln_kernel<<<NROWS/4, 256, 0, stream>>>(tokens, emb, ln1_g, ln1_b, x, hb);

    const int gQKV = 6*(NROWS/128);   // 2280
    const int gO   = 2*(NROWS/128);   // 760
    const int gF1  = 8*(HROWS/128);   // 1520
    const int gF2  = 2*(HROWS/128);   // 380

    for (int i = 0; i < NBLK; ++i) {
        // ---- row attention (pair axis, L=190 padded to 192) ----
        if (i > 0)
            ln_kernel<<<NROWS/4, 256, 0, stream>>>(x, ln1_g + i*HDIM, ln1_b + i*HDIM, hb);
        mgemm_kernel<0><<<gQKV, 256, 0, stream>>>(hb, w_rqkv + (size_t)i*QZ, nullptr, nullptr, q, k, v, 256, 768, 6);
        attn_mfma<192><<<BDIM*CDIM*NHEADS, 512, 0, stream>>>(q, k, v, hb, PDIM, 1);
        mgemm_kernel<1><<<gO, 256, 0, stream>>>(hb, w_ro + i*HH, nullptr, x, nullptr, nullptr, nullptr, 256, 256, 2);

        // ---- column attention (L=128) ----
        ln_kernel<<<NROWS/4, 256, 0, stream>>>(x, ln2_g + i*HDIM, ln2_b + i*HDIM, hb);
        mgemm_kernel<0><<<gQKV, 256, 0, stream>>>(hb, w_cqkv + (size_t)i*QZ, nullptr, nullptr, q, k, v, 256, 768, 6);
        attn_mfma<128><<<BDIM*PDIM*NHEADS, 512, 0, stream>>>(q, k, v, hb, CDIM, 0);
        mgemm_kernel<1><<<gO, 256, 0, stream>>>(hb, w_co + i*HH, nullptr, x, nullptr, nullptr, nullptr, 256, 256, 2);

        // ---- FFN ----
        ln_kernel<<<NROWS/4, 256, 0, stream>>>(x, ln3_g + i*HDIM, ln3_b + i*HDIM, hb);
        for (int ch = 0; ch < 2; ++ch) {
            const size_t ro = (size_t)ch*HROWS*HDIM;
            mgemm_kernel<2><<<gF1, 256, 0, stream>>>(hb + ro, w_f1 + (size_t)i*HF,
                                                     fb1 + i*FDIM, nullptr, tb, nullptr, nullptr, 256, 1024, 8);
            if (i < NBLK-1)
                mgemm_kernel<3><<<gF2, 256, 0, stream>>>(tb, w_f2 + (size_t)i*HF,
                                                         fb2 + i*HDIM, x + ro,
                                                         nullptr, nullptr, nullptr, 1024, 256, 2);
            else
                mgemm_kernel<4><<<gF2, 256, 0, stream>>>(tb, w_f2 + (size_t)i*HF,
                                                         fb2 + i*HDIM, x + ro,
                                                         hb + ro, nullptr, nullptr, 1024, 256, 2);
        }
    }

    // ---- head: hb holds bf16(x) from EPI4 ----
    for (int ch = 0; ch < 2; ++ch) {
        const size_t ro = (size_t)ch*HROWS*HDIM;
        mgemm_kernel<2><<<gF1, 256, 0, stream>>>(hb + ro, w_p1, pb1, nullptr, tb, nullptr, nullptr, 256, 1024, 8);
        gemv_head<<<HROWS/4, 256, 0, stream>>>(tb, pW2, pb2, y + (size_t)ch*HROWS);
    }
    final_kernel<<<BDIM*PDIM, 128, 0, stream>>>(y, uW, ub, (float*)d_out);
}

// Round 17
// 1438.857 us; speedup vs baseline: 1.0277x; 1.0277x over previous
//
#include <hip/hip_runtime.h>
#include <hip/hip_bf16.h>
#include <stdint.h>

#define NBLK   4
#define HDIM   256
#define NHEADS 8
#define RDIM   20
#define CDIM   128
#define PDIM   190
#define BDIM   2
#define FDIM   1024
#define NROWS  (BDIM*PDIM*CDIM)             // 48640
#define NF     ((size_t)NROWS*(size_t)HDIM) // 12,451,840
#define HROWS  (NROWS/2)                    // 24320

typedef __attribute__((ext_vector_type(8))) short bf16x8;
typedef __attribute__((ext_vector_type(4))) float f32x4;

__device__ __forceinline__ short f2b(float f){
    uint32_t u = __float_as_uint(f);
    u += 0x7fff + ((u >> 16) & 1);          // RNE
    return (short)(u >> 16);
}
__device__ __forceinline__ float b2f(short s){
    return __uint_as_float(((uint32_t)(uint16_t)s) << 16);
}
__device__ __forceinline__ int cvtpk(float a, float b){
    int r;
    asm("v_cvt_pk_bf16_f32 %0, %1, %2" : "=v"(r) : "v"(a), "v"(b));
    return r;
}
// gelu(tanh approx) == x * sigmoid(2*k0*(x + k1*x^3))
__device__ __forceinline__ float gelu_fast(float x){
    const float tk0 = 1.5957691216057308f;   // 2*sqrt(2/pi)
    const float k1  = 0.044715f;
    float u = tk0*(x + k1*x*x*x);
    return x / (1.0f + __expf(-u));
}
__device__ __forceinline__ void async16(const void* g, void* l){
    __builtin_amdgcn_global_load_lds(
        (const __attribute__((address_space(1))) void*)g,
        (__attribute__((address_space(3))) void*)l, 16, 0, 0);
}
// bijective XCD-chunking swizzle (m204)
__device__ __forceinline__ int xcd_swz(int nwg){
    int orig = blockIdx.x;
    int q = nwg >> 3, r = nwg & 7;
    int xcd = orig & 7, idx = orig >> 3;
    return ((xcd < r) ? xcd*(q+1) : r*(q+1) + (xcd - r)*q) + idx;
}

// ---------------------------------------------------------------------------
// Embedding + pairwise row-sum + fused LN1(block0). One wave per row.
// ---------------------------------------------------------------------------
__global__ __launch_bounds__(256) void embed_ln_kernel(
    const int* __restrict__ tokens, const float* __restrict__ emb,
    const float* __restrict__ g, const float* __restrict__ bta,
    float* __restrict__ x, short* __restrict__ hb)
{
    int n    = blockIdx.x*4 + (threadIdx.x >> 6);
    int lane = threadIdx.x & 63;
    int c  = n % CDIM;
    int bp = n / CDIM;
    int p  = bp % PDIM;
    int b  = bp / PDIM;
    int i = 0, rem = p;
    while (rem >= (RDIM - 1 - i)) { rem -= (RDIM - 1 - i); ++i; }
    int j = i + 1 + rem;
    int t1 = tokens[(b*RDIM + i)*CDIM + c];
    int t2 = tokens[(b*RDIM + j)*CDIM + c];
    float4 e1 = *(const float4*)(emb + (size_t)t1*HDIM + lane*4);
    float4 e2 = *(const float4*)(emb + (size_t)t2*HDIM + lane*4);
    float4 v; v.x = e1.x+e2.x; v.y = e1.y+e2.y; v.z = e1.z+e2.z; v.w = e1.w+e2.w;
    *(float4*)(x + (size_t)n*HDIM + lane*4) = v;

    float s1 = v.x + v.y + v.z + v.w;
    float s2 = v.x*v.x + v.y*v.y + v.z*v.z + v.w*v.w;
    #pragma unroll
    for (int off = 1; off < 64; off <<= 1) {
        s1 += __shfl_xor(s1, off);
        s2 += __shfl_xor(s2, off);
    }
    float mu  = s1 * (1.0f/HDIM);
    float var = s2 * (1.0f/HDIM) - mu*mu;
    float inv = rsqrtf(var + 1e-5f);
    float4 gg = *(const float4*)(g   + lane*4);
    float4 bb = *(const float4*)(bta + lane*4);
    short4 o;
    o.x = f2b((v.x - mu)*inv*gg.x + bb.x);
    o.y = f2b((v.y - mu)*inv*gg.y + bb.y);
    o.z = f2b((v.z - mu)*inv*gg.z + bb.z);
    o.w = f2b((v.w - mu)*inv*gg.w + bb.w);
    *(short4*)(hb + (size_t)n*HDIM + lane*4) = o;
}

// ---------------------------------------------------------------------------
// LayerNorm fp32 -> bf16. One wave per row, float4 per lane.
// ---------------------------------------------------------------------------
__global__ __launch_bounds__(256) void ln_kernel(
    const float* __restrict__ X, const float* __restrict__ g,
    const float* __restrict__ bta, short* __restrict__ Out)
{
    int row  = blockIdx.x*4 + (threadIdx.x >> 6);
    int lane = threadIdx.x & 63;
    float4 v = *(const float4*)(X + (size_t)row*HDIM + lane*4);
    float s1 = v.x + v.y + v.z + v.w;
    float s2 = v.x*v.x + v.y*v.y + v.z*v.z + v.w*v.w;
    #pragma unroll
    for (int off = 1; off < 64; off <<= 1) {
        s1 += __shfl_xor(s1, off);
        s2 += __shfl_xor(s2, off);
    }
    float mu  = s1 * (1.0f/HDIM);
    float var = s2 * (1.0f/HDIM) - mu*mu;
    float inv = rsqrtf(var + 1e-5f);
    float4 gg = *(const float4*)(g   + lane*4);
    float4 bb = *(const float4*)(bta + lane*4);
    short4 o;
    o.x = f2b((v.x - mu)*inv*gg.x + bb.x);
    o.y = f2b((v.y - mu)*inv*gg.y + bb.y);
    o.z = f2b((v.z - mu)*inv*gg.z + bb.z);
    o.w = f2b((v.w - mu)*inv*gg.w + bb.w);
    *(short4*)(Out + (size_t)row*HDIM + lane*4) = o;
}

// ---------------------------------------------------------------------------
// Weight transpose+convert: in f32 [K][M] -> out bf16 [M][K]
// ---------------------------------------------------------------------------
__global__ __launch_bounds__(256) void tconv_kernel(
    const float* __restrict__ in, short* __restrict__ out,
    int K, int M, size_t inz, size_t outz)
{
    __shared__ float t[32][33];
    in  += (size_t)blockIdx.z * inz;
    out += (size_t)blockIdx.z * outz;
    int m0 = blockIdx.x*32, k0 = blockIdx.y*32;
    int r = threadIdx.x >> 5, c = threadIdx.x & 31;
    #pragma unroll
    for (int i = 0; i < 4; ++i)
        t[r + i*8][c] = in[(size_t)(k0 + r + i*8)*M + m0 + c];
    __syncthreads();
    #pragma unroll
    for (int i = 0; i < 4; ++i) {
        int rr = r + i*8;
        out[(size_t)(m0 + rr)*K + k0 + c] = f2b(t[c][rr]);
    }
}

// ---------------------------------------------------------------------------
// bf16 MFMA GEMM, 2-buffer prefetch + LDS-staged coalesced bf16 C-stores.
// EPI 0: QKV split store bf16 (Q pre-scaled by log2(e)/sqrt(d) for exp2 attn)
// EPI 1: OutF += acc
// EPI 2: bf16(gelu(acc+bias))
// EPI 3: OutF += acc + bias
// EPI 4: OutF += acc + bias; OB0 = bf16(result)
// ---------------------------------------------------------------------------
template<int EPI>
__global__ __launch_bounds__(256) void mgemm_kernel(
    const short* __restrict__ A, const short* __restrict__ Wt,
    const float* __restrict__ bias,
    float* __restrict__ OutF,
    short* __restrict__ OB0, short* __restrict__ OB1, short* __restrict__ OB2,
    int K, int M, int ncol)
{
    __shared__ __align__(16) short smem[16384];   // As[2]+Bs[2]; reused as C[128][128]
    short* As0 = smem;
    short* Bs0 = smem + 8192;
    const int tid  = threadIdx.x;
    const int lane = tid & 63, wid = tid >> 6;
    const int lq = lane & 15, lk = lane >> 4;
    const int wr = wid >> 1, wc = wid & 1;
    const int bid  = xcd_swz(gridDim.x);
    const int row0 = (bid / ncol) * 128, col0 = (bid % ncol) * 128;

    f32x4 acc[4][4] = {};

    auto stage = [&](int buf, int k0) {
        #pragma unroll
        for (int u = 0; u < 2; ++u) {
            int b   = wid*1024 + lane*16 + u*4096;
            int r   = b >> 6;
            int c16 = (b >> 4) & 3;
            int cs  = (c16 ^ ((r >> 1) & 3)) * 8;
            async16(A  + (size_t)(row0 + r)*K + k0 + cs, (char*)(As0 + buf*4096) + b);
            async16(Wt + (size_t)(col0 + r)*K + k0 + cs, (char*)(Bs0 + buf*4096) + b);
        }
    };

    stage(0, 0);
    const int NTK = K >> 5;
    for (int t = 0; t < NTK; ++t) {
        const int cur = t & 1;
        asm volatile("s_waitcnt vmcnt(0)" ::: "memory");
        __builtin_amdgcn_s_barrier();
        __builtin_amdgcn_sched_barrier(0);
        if (t + 1 < NTK) stage(cur ^ 1, (t + 1)*32);

        bf16x8 af[4], bfr[4];
        #pragma unroll
        for (int m = 0; m < 4; ++m) {
            int row = wr*64 + m*16 + lq;
            af[m] = *(const bf16x8*)((const char*)(As0 + cur*4096) + row*64 + ((lk ^ ((lq >> 1) & 3)) << 4));
        }
        #pragma unroll
        for (int n = 0; n < 4; ++n) {
            int row = wc*64 + n*16 + lq;
            bfr[n] = *(const bf16x8*)((const char*)(Bs0 + cur*4096) + row*64 + ((lk ^ ((lq >> 1) & 3)) << 4));
        }
        #pragma unroll
        for (int m = 0; m < 4; ++m)
            #pragma unroll
            for (int n = 0; n < 4; ++n)
                acc[m][n] = __builtin_amdgcn_mfma_f32_16x16x32_bf16(af[m], bfr[n], acc[m][n], 0, 0, 0);
    }

    // D layout: row = (lane>>4)*4 + reg, col = lane&15
    if (EPI == 1 || EPI == 3) {
        const int rb  = row0 + wr*64 + (lk << 2);
        const int cb0 = col0 + wc*64 + lq;
        #pragma unroll
        for (int m = 0; m < 4; ++m)
            #pragma unroll
            for (int n = 0; n < 4; ++n) {
                int col = cb0 + n*16;
                #pragma unroll
                for (int r = 0; r < 4; ++r) {
                    int row = rb + m*16 + r;
                    float vv = acc[m][n][r];
                    if (EPI == 3) vv += bias[col];
                    OutF[(size_t)row*HDIM + col] += vv;
                }
            }
        return;
    }

    // ---- bf16 epilogues: transform -> LDS C-stage -> coalesced 16B stores
    float bias8[4];
    if (EPI == 2 || EPI == 4) {
        #pragma unroll
        for (int n = 0; n < 4; ++n) bias8[n] = bias[col0 + wc*64 + n*16 + lq];
    }
    const int sec = col0 >> 8;                     // EPI0: uniform per block
    // Q pre-scale: log2(e)/sqrt(32) so attn uses native v_exp_f32 (2^x)
    const float qsc = (EPI == 0 && sec == 0) ? 0.2550540018992861f : 1.0f;

    __syncthreads();   // all waves done reading staging LDS
    #pragma unroll
    for (int m = 0; m < 4; ++m) {
        #pragma unroll
        for (int n = 0; n < 4; ++n) {
            #pragma unroll
            for (int r = 0; r < 4; ++r) {
                int lrow = wr*64 + m*16 + lk*4 + r;
                int lcol = wc*64 + n*16 + lq;
                float vv = acc[m][n][r];
                if (EPI == 0) vv *= qsc;
                else if (EPI == 2) vv = gelu_fast(vv + bias8[n]);
                else { // EPI 4
                    int row = row0 + lrow, col = col0 + lcol;
                    float xo = OutF[(size_t)row*HDIM + col] + vv + bias8[n];
                    OutF[(size_t)row*HDIM + col] = xo;
                    vv = xo;
                }
                int byte = (lrow*256 + lcol*2) ^ ((lrow & 7) << 4);
                *(short*)((char*)smem + byte) = (short)cvtpk(vv, vv);
            }
        }
    }
    __syncthreads();

    short* obase;
    int ostride, ocol;
    if (EPI == 0) {
        obase = (sec == 0) ? OB0 : ((sec == 1) ? OB1 : OB2);
        ostride = HDIM; ocol = col0 & 255;
    } else if (EPI == 2) {
        obase = OB0; ostride = M; ocol = col0;
    } else {
        obase = OB0; ostride = HDIM; ocol = col0;
    }
    #pragma unroll
    for (int it = 0; it < 8; ++it) {
        int u    = it*256 + tid;
        int lrow = u >> 4;
        int uc   = u & 15;
        int su   = uc ^ (lrow & 7);
        int4 w = *(const int4*)((const char*)smem + lrow*256 + su*16);
        *(int4*)(obase + (size_t)(row0 + lrow)*ostride + ocol + uc*8) = w;
    }
}

// ---------------------------------------------------------------------------
// MFMA attention. One block per (b,other,head); 4 waves; XCD-swizzled grid.
// Q pre-scaled by log2(e)/sqrt(d) -> softmax in exp2 domain (native v_exp).
// No max-sub (clamp 126); denominator via ones-B MFMA in PV loop.
// O-store coalesced: per-wave 16x32 tile staged in P-LDS (lk-XOR on 16B
// units) then flushed with ds_read_b128 + global_store_dwordx4 (64B rows).
// ---------------------------------------------------------------------------
template<int LP>
__global__ __launch_bounds__(256) void attn_mfma(
    const short* __restrict__ Q, const short* __restrict__ K,
    const short* __restrict__ V, short* __restrict__ O,
    int Lreal, int isRow)
{
    constexpr int NT  = LP/16;
    constexpr int NKT = LP/32;
    constexpr int NCH = LP/64;
    constexpr int LPB = LP*2;

    __shared__ short Ks[LP*32];
    __shared__ short Vt[32*LP];
    __shared__ short Ps[4*16*LP];

    const int bid  = xcd_swz(gridDim.x);
    const int head = bid & 7;
    size_t base; int S;
    if (isRow) {
        int c = (bid >> 3) & (CDIM-1);
        int b = bid >> 10;
        base = ((size_t)b*PDIM*CDIM + c)*HDIM + head*32;
        S = CDIM*HDIM;
    } else {
        int p = (bid >> 3) % PDIM;
        int b = bid / (8*PDIM);
        base = ((size_t)(b*PDIM + p)*CDIM)*HDIM + head*32;
        S = HDIM;
    }

    const int tid  = threadIdx.x;
    const int lane = tid & 63, wid = tid >> 6;
    const int lq = lane & 15, lk = lane >> 4;

    // ---- stage K [LP][32]: linear LDS dest, source-swizzled 16B units
    #pragma unroll
    for (int it = 0; it < LP/64; ++it) {
        int t16 = it*256 + tid;
        int row = t16 >> 2;
        int rc  = row < Lreal ? row : Lreal-1;
        int cs  = ((t16 & 3) ^ ((row >> 1) & 3)) * 8;
        async16(K + base + (size_t)rc*S + cs, (char*)Ks + (size_t)t16*16);
    }
    // ---- stage V transposed with XOR swizzle: Vt[d][key], byte ^= (d&7)<<4
    #pragma unroll
    for (int it = 0; it < LP/32; ++it) {
        int e   = it*256 + tid;
        int row = e >> 3;
        int d4  = (e & 7)*4;
        int rc  = row < Lreal ? row : Lreal-1;
        short4 v4 = *(const short4*)(V + base + (size_t)rc*S + d4);
        #pragma unroll
        for (int j = 0; j < 4; ++j) {
            int d = d4 + j;
            int off = ((d*LP + row)*2) ^ ((d & 7) << 4);
            *(short*)((char*)Vt + off) = ((const short*)&v4)[j];
        }
    }
    __syncthreads();

    char* pbase = (char*)Ps + wid*(16*LPB);
    const f32x4 zero = {0.f, 0.f, 0.f, 0.f};
    const bf16x8 ones = {(short)0x3F80,(short)0x3F80,(short)0x3F80,(short)0x3F80,
                         (short)0x3F80,(short)0x3F80,(short)0x3F80,(short)0x3F80};

    #pragma unroll 1
    for (int cc = 0; cc < NCH; ++cc) {
        const int chunk = wid + cc*4;
        const int qrow0 = chunk*16;

        int qr = qrow0 + lq; if (qr >= Lreal) qr = Lreal-1;
        bf16x8 qa = *(const bf16x8*)(Q + base + (size_t)qr*S + lk*8);

        f32x4 s[NT];
        #pragma unroll
        for (int t = 0; t < NT; ++t) {
            bf16x8 kb = *(const bf16x8*)((const char*)Ks + (t*16 + lq)*64 + ((lk ^ ((lq >> 1) & 3)) << 4));
            s[t] = __builtin_amdgcn_mfma_f32_16x16x32_bf16(qa, kb, zero, 0, 0, 0);
        }
        if ((NT-1)*16 + lq >= Lreal) {
            #pragma unroll
            for (int r = 0; r < 4; ++r) s[NT-1][r] = -1e30f;
        }

        // P = exp2(s) -> bf16 LDS (s already in log2 domain; dead keys -> 0)
        #pragma unroll
        for (int t = 0; t < NT; ++t)
            #pragma unroll
            for (int r = 0; r < 4; ++r) {
                float p = exp2f(fminf(s[t][r], 126.f));
                int row = lk*4 + r, col = t*16 + lq;
                int off = (row*LPB + col*2) ^ ((row & 7) << 4);
                *(short*)(pbase + off) = (short)cvtpk(p, p);
            }
        asm volatile("s_waitcnt lgkmcnt(0)" ::: "memory");
        __builtin_amdgcn_sched_barrier(0);

        // PV + ones-denominator
        f32x4 acc0 = zero, acc1 = zero, accs = zero;
        #pragma unroll
        for (int kt = 0; kt < NKT; ++kt) {
            bf16x8 pa = *(const bf16x8*)(pbase + ((lq*LPB + kt*64 + lk*16) ^ ((lq & 7) << 4)));
            bf16x8 v0 = *(const bf16x8*)((char*)Vt + ((lq*LPB      + kt*64 + lk*16) ^ ((lq & 7) << 4)));
            bf16x8 v1 = *(const bf16x8*)((char*)Vt + (((16+lq)*LPB + kt*64 + lk*16) ^ ((lq & 7) << 4)));
            acc0 = __builtin_amdgcn_mfma_f32_16x16x32_bf16(pa, v0, acc0, 0, 0, 0);
            acc1 = __builtin_amdgcn_mfma_f32_16x16x32_bf16(pa, v1, acc1, 0, 0, 0);
            accs = __builtin_amdgcn_mfma_f32_16x16x32_bf16(pa, ones, accs, 0, 0, 0);
        }
        asm volatile("s_waitcnt lgkmcnt(0)" ::: "memory");   // PV LDS reads done
        __builtin_amdgcn_sched_barrier(0);

        // ---- coalesced O-store: stage 16x32 bf16 tile in pbase (lk-XOR units)
        #pragma unroll
        for (int r = 0; r < 4; ++r) {
            float inv = 1.0f / accs[r];
            int row = lk*4 + r;
            int b0 = row*64 + ((lq*2)        ^ (lk << 4));
            int b1 = row*64 + ((32 + lq*2)   ^ (lk << 4));
            *(short*)(pbase + b0) = (short)cvtpk(acc0[r]*inv, acc0[r]*inv);
            *(short*)(pbase + b1) = (short)cvtpk(acc1[r]*inv, acc1[r]*inv);
        }
        asm volatile("s_waitcnt lgkmcnt(0)" ::: "memory");
        __builtin_amdgcn_sched_barrier(0);
        {
            int rr  = lane >> 2, uc = lane & 3;
            int row = qrow0 + rr;
            if (row < Lreal) {
                int lkw = rr >> 2;                      // writer's lk for this row
                int4 w = *(const int4*)(pbase + rr*64 + uc*16);
                *(int4*)(O + base + (size_t)row*S + (uc ^ lkw)*8) = w;
            }
        }
        __builtin_amdgcn_sched_barrier(0);   // keep next chunk's P writes behind these reads
    }
}

// ---------------------------------------------------------------------------
__global__ __launch_bounds__(256) void gemv_head(
    const short* __restrict__ T, const float* __restrict__ w,
    const float* __restrict__ bias, float* __restrict__ y)
{
    int row  = blockIdx.x*4 + (threadIdx.x >> 6);
    int lane = threadIdx.x & 63;
    const short* t = T + (size_t)row*FDIM;
    float acc = 0.f;
    #pragma unroll
    for (int it = 0; it < 4; ++it) {
        int ci = it*64 + lane;
        short4 tv = *(const short4*)(t + ci*4);
        float4 wv = *(const float4*)(w + ci*4);
        acc += b2f(tv.x)*wv.x + b2f(tv.y)*wv.y + b2f(tv.z)*wv.z + b2f(tv.w)*wv.w;
    }
    #pragma unroll
    for (int off = 1; off < 64; off <<= 1) acc += __shfl_xor(acc, off);
    if (lane == 0) y[row] = acc + bias[0];
}

__global__ __launch_bounds__(128) void final_kernel(
    const float* __restrict__ y, const float* __restrict__ uW,
    const float* __restrict__ ub, float* __restrict__ out)
{
    int bp = blockIdx.x;
    int c  = threadIdx.x;
    float v = y[(size_t)bp*CDIM + c]*uW[c];
    #pragma unroll
    for (int off = 1; off < 64; off <<= 1) v += __shfl_xor(v, off);
    __shared__ float r[2];
    if ((c & 63) == 0) r[c >> 6] = v;
    __syncthreads();
    if (c == 0) out[bp] = r[0] + r[1] + ub[0];
}

// ---------------------------------------------------------------------------
extern "C" void kernel_launch(void* const* d_in, const int* in_sizes, int n_in,
                              void* d_out, int out_size, void* d_ws, size_t ws_size,
                              hipStream_t stream)
{
    const int*   tokens = (const int*)  d_in[0];
    const float* emb    = (const float*)d_in[1];
    const float* ln1_g  = (const float*)d_in[2];
    const float* ln1_b  = (const float*)d_in[3];
    const float* rWq    = (const float*)d_in[4];
    const float* rWk    = (const float*)d_in[5];
    const float* rWv    = (const float*)d_in[6];
    const float* rWo    = (const float*)d_in[7];
    const float* ln2_g  = (const float*)d_in[8];
    const float* ln2_b  = (const float*)d_in[9];
    const float* cWq    = (const float*)d_in[10];
    const float* cWk    = (const float*)d_in[11];
    const float* cWv    = (const float*)d_in[12];
    const float* cWo    = (const float*)d_in[13];
    const float* ln3_g  = (const float*)d_in[14];
    const float* ln3_b  = (const float*)d_in[15];
    const float* fW1    = (const float*)d_in[16];
    const float* fb1    = (const float*)d_in[17];
    const float* fW2    = (const float*)d_in[18];
    const float* fb2    = (const float*)d_in[19];
    const float* pW1    = (const float*)d_in[20];
    const float* pb1    = (const float*)d_in[21];
    const float* pW2    = (const float*)d_in[22];
    const float* pb2    = (const float*)d_in[23];
    const float* uW     = (const float*)d_in[24];
    const float* ub     = (const float*)d_in[25];

    float* x  = (float*)d_ws;
    short* q  = (short*)(x + NF);
    short* k  = q + NF;
    short* v  = k + NF;
    short* hb = v + NF;
    float* y  = (float*)(hb + NF);
    short* wts = (short*)(y + NROWS);
    short* w_rqkv = wts;
    short* w_cqkv = w_rqkv + 4*768*256;
    short* w_ro   = w_cqkv + 4*768*256;
    short* w_co   = w_ro   + 4*256*256;
    short* w_f1   = w_co   + 4*256*256;
    short* w_f2   = w_f1   + (size_t)4*1024*256;
    short* w_p1   = w_f2   + (size_t)4*1024*256;
    short* tb = q;

    const size_t HH = 65536, HF = 262144, QZ = 768*256;

    tconv_kernel<<<dim3(8,8,NBLK),   256, 0, stream>>>(rWq, w_rqkv,          256, 256,  HH, QZ);
    tconv_kernel<<<dim3(8,8,NBLK),   256, 0, stream>>>(rWk, w_rqkv + 65536,  256, 256,  HH, QZ);
    tconv_kernel<<<dim3(8,8,NBLK),   256, 0, stream>>>(rWv, w_rqkv + 131072, 256, 256,  HH, QZ);
    tconv_kernel<<<dim3(8,8,NBLK),   256, 0, stream>>>(rWo, w_ro,            256, 256,  HH, HH);
    tconv_kernel<<<dim3(8,8,NBLK),   256, 0, stream>>>(cWq, w_cqkv,          256, 256,  HH, QZ);
    tconv_kernel<<<dim3(8,8,NBLK),   256, 0, stream>>>(cWk, w_cqkv + 65536,  256, 256,  HH, QZ);
    tconv_kernel<<<dim3(8,8,NBLK),   256, 0, stream>>>(cWv, w_cqkv + 131072, 256, 256,  HH, QZ);
    tconv_kernel<<<dim3(8,8,NBLK),   256, 0, stream>>>(cWo, w_co,            256, 256,  HH, HH);
    tconv_kernel<<<dim3(32,8,NBLK),  256, 0, stream>>>(fW1, w_f1,            256, 1024, HF, HF);
    tconv_kernel<<<dim3(8,32,NBLK),  256, 0, stream>>>(fW2, w_f2,            1024, 256, HF, HF);
    tconv_kernel<<<dim3(32,8,1),     256, 0, stream>>>(pW1, w_p1,            256, 1024, HF, HF);

    embed_ln_kernel<<<NROWS/4, 256, 0, stream>>>(tokens, emb, ln1_g, ln1_b, x, hb);

    const int gQKV = 6*(NROWS/128);   // 2280
    const int gO   = 2*(NROWS/128);   // 760
    const int gF1  = 8*(HROWS/128);   // 1520
    const int gF2  = 2*(HROWS/128);   // 380

    for (int i = 0; i < NBLK; ++i) {
        // ---- row attention (pair axis, L=190 padded to 192) ----
        if (i > 0)
            ln_kernel<<<NROWS/4, 256, 0, stream>>>(x, ln1_g + i*HDIM, ln1_b + i*HDIM, hb);
        mgemm_kernel<0><<<gQKV, 256, 0, stream>>>(hb, w_rqkv + (size_t)i*QZ, nullptr, nullptr, q, k, v, 256, 768, 6);
        attn_mfma<192><<<BDIM*CDIM*NHEADS, 256, 0, stream>>>(q, k, v, hb, PDIM, 1);
        mgemm_kernel<1><<<gO, 256, 0, stream>>>(hb, w_ro + i*HH, nullptr, x, nullptr, nullptr, nullptr, 256, 256, 2);

        // ---- column attention (L=128) ----
        ln_kernel<<<NROWS/4, 256, 0, stream>>>(x, ln2_g + i*HDIM, ln2_b + i*HDIM, hb);
        mgemm_kernel<0><<<gQKV, 256, 0, stream>>>(hb, w_cqkv + (size_t)i*QZ, nullptr, nullptr, q, k, v, 256, 768, 6);
        attn_mfma<128><<<BDIM*PDIM*NHEADS, 256, 0, stream>>>(q, k, v, hb, CDIM, 0);
        mgemm_kernel<1><<<gO, 256, 0, stream>>>(hb, w_co + i*HH, nullptr, x, nullptr, nullptr, nullptr, 256, 256, 2);

        // ---- FFN ----
        ln_kernel<<<NROWS/4, 256, 0, stream>>>(x, ln3_g + i*HDIM, ln3_b + i*HDIM, hb);
        for (int ch = 0; ch < 2; ++ch) {
            const size_t ro = (size_t)ch*HROWS*HDIM;
            mgemm_kernel<2><<<gF1, 256, 0, stream>>>(hb + ro, w_f1 + (size_t)i*HF,
                                                     fb1 + i*FDIM, nullptr, tb, nullptr, nullptr, 256, 1024, 8);
            if (i < NBLK-1)
                mgemm_kernel<3><<<gF2, 256, 0, stream>>>(tb, w_f2 + (size_t)i*HF,
                                                         fb2 + i*HDIM, x + ro,
                                                         nullptr, nullptr, nullptr, 1024, 256, 2);
            else
                mgemm_kernel<4><<<gF2, 256, 0, stream>>>(tb, w_f2 + (size_t)i*HF,
                                                         fb2 + i*HDIM, x + ro,
                                                         hb + ro, nullptr, nullptr, 1024, 256, 2);
        }
    }

    // ---- head: hb holds bf16(x) from EPI4 ----
    for (int ch = 0; ch < 2; ++ch) {
        const size_t ro = (size_t)ch*HROWS*HDIM;
        mgemm_kernel<2><<<gF1, 256, 0, stream>>>(hb + ro, w_p1, pb1, nullptr, tb, nullptr, nullptr, 256, 1024, 8);
        gemv_head<<<HROWS/4, 256, 0, stream>>>(tb, pW2, pb2, y + (size_t)ch*HROWS);
    }
    final_kernel<<<BDIM*PDIM, 128, 0, stream>>>(y, uW, ub, (float*)d_out);
}